// Round 9
// baseline (276.835 us; speedup 1.0000x reference)
//
#include <hip/hip_runtime.h>

#define N_PTS   20000
#define M_ATOMS 10000
#define DAT     64
#define HID     129
#define KNN     16
#define NLAYERS 3

#define A_HSTRIDE  132        // A row stride in HALVES (264 B, 8B-aligned)
#define PTS_L      2          // points per wave in layer kernel

#define GRIDL   48
#define NCELL   (GRIDL*GRIDL*GRIDL)   // 110592
#define CELL_H  2.0f
#define INV_H   0.5f
#define GORIG   (-48.0f)
#define SCAN_NBLK (NCELL / 256)       // 432
#define EXPCAP  1024                  // per-wave LDS candidate buffer

typedef _Float16 half2_t __attribute__((ext_vector_type(2)));

__device__ __forceinline__ float readlane_f(float v, int l) {
    return __int_as_float(__builtin_amdgcn_readlane(__float_as_int(v), l));
}
__device__ __forceinline__ int cell_of(float v) {
    int c = (int)floorf((v - GORIG) * INV_H);
    return c < 0 ? 0 : (c > GRIDL - 1 ? GRIDL - 1 : c);
}

// ================= grid build =================
__global__ void grid_zero(int* __restrict__ cnts) {
    int i = blockIdx.x * 256 + threadIdx.x;
    if (i < NCELL) cnts[i] = 0;
}

__global__ void grid_count(const float* __restrict__ y, int* __restrict__ cnts) {
    int i = blockIdx.x * 256 + threadIdx.x;
    if (i >= M_ATOMS) return;
    float a = y[3*i], b = y[3*i+1], c = y[3*i+2];
    int cid = (cell_of(c) * GRIDL + cell_of(b)) * GRIDL + cell_of(a);
    atomicAdd(&cnts[cid], 1);
}

__global__ void scanA(const int* __restrict__ cnts, int* __restrict__ bsum) {
    __shared__ int red[256];
    int t = threadIdx.x;
    red[t] = cnts[blockIdx.x * 256 + t];
    for (int o = 128; o; o >>= 1) {
        __syncthreads();
        if (t < o) red[t] += red[t + o];
    }
    if (t == 0) bsum[blockIdx.x] = red[0];
}

__global__ __launch_bounds__(512) void scanB(const int* __restrict__ bsum,
        int* __restrict__ boff, int* __restrict__ starts) {
    __shared__ int s[512];
    int t = threadIdx.x;
    int v = (t < SCAN_NBLK) ? bsum[t] : 0;
    s[t] = v;
    for (int o = 1; o < 512; o <<= 1) {
        __syncthreads();
        int u = (t >= o) ? s[t - o] : 0;
        __syncthreads();
        s[t] += u;
    }
    __syncthreads();
    if (t < SCAN_NBLK) boff[t] = s[t] - v;        // exclusive block offset
    if (t == SCAN_NBLK - 1) starts[NCELL] = s[t]; // total
}

__global__ void scanC(int* __restrict__ cnts /*in: counts, out: cursor*/,
        const int* __restrict__ boff, int* __restrict__ starts) {
    __shared__ int s[256];
    int t = threadIdx.x, i = blockIdx.x * 256 + t;
    int v = cnts[i];
    s[t] = v;
    for (int o = 1; o < 256; o <<= 1) {
        __syncthreads();
        int u = (t >= o) ? s[t - o] : 0;
        __syncthreads();
        s[t] += u;
    }
    __syncthreads();
    int ex = s[t] - v + boff[blockIdx.x];
    starts[i] = ex;
    cnts[i]   = ex;                                // becomes scatter cursor
}

__global__ void grid_scatter(const float* __restrict__ y, int* __restrict__ cursor,
                             float4* __restrict__ ypc, int* __restrict__ aidx) {
    int i = blockIdx.x * 256 + threadIdx.x;
    if (i >= M_ATOMS) return;
    float a = y[3*i], b = y[3*i+1], c = y[3*i+2];
    int cid = (cell_of(c) * GRIDL + cell_of(b)) * GRIDL + cell_of(a);
    int pos = atomicAdd(&cursor[cid], 1);
    ypc[pos]  = make_float4(a, b, c, (a*a + b*b) + c*c);   // (y**2).sum(1) order
    aidx[pos] = i;
}

// ================= grid kNN query =================
// Top-16 in lanes 0..15 sorted ascending by (d2, idx) lexicographic ==
// jax.lax.top_k tie semantics; deterministic regardless of traversal order.
__device__ __forceinline__ void topk_process(float d2, int ai, int lane,
        float& Ld, int& Li, float& kth, int& kidx, bool& filled) {
    const float INF = __builtin_inff();
    if (!filled) {                                  // bitonic-sort fill (wave-uniform)
        float v = d2; int ix = ai;
#pragma unroll
        for (int k = 2; k <= 64; k <<= 1)
#pragma unroll
            for (int j = k >> 1; j > 0; j >>= 1) {
                float ov = __shfl_xor(v, j);
                int   oi = __shfl_xor(ix, j);
                bool keepmin = (((lane & k) == 0) == ((lane & j) == 0));
                bool oless   = (ov < v) || (ov == v && oi < ix);
                bool take    = (keepmin == oless);
                v  = take ? ov : v;
                ix = take ? oi : ix;
            }
        Ld = (lane < KNN) ? v : INF;
        Li = (lane < KNN) ? ix : 0x7fffffff;
        kth  = readlane_f(v, 15);
        kidx = __builtin_amdgcn_readlane(ix, 15);
        filled = true;
        return;
    }
    bool adm = (d2 < kth) || (d2 == kth && ai < kidx);
    unsigned long long cand = __ballot(adm);
    if (cand) {
        do {
            int src = __builtin_ctzll(cand);
            cand &= cand - 1;
            float v  = readlane_f(d2, src);
            int   mi = __builtin_amdgcn_readlane(ai, src);
            bool pred = (Ld > v) || (Ld == v && Li > mi);   // lexicographic
            unsigned long long bal = __ballot(pred);
            int ins = __builtin_ctzll(bal);
            float pd = __shfl_up(Ld, 1);
            int   pi = __shfl_up(Li, 1);
            bool atins = (lane == ins);
            float tv = atins ? v  : pd;
            int   ti = atins ? mi : pi;
            Ld = pred ? tv : Ld;
            Li = pred ? ti : Li;
        } while (cand);
        kth  = readlane_f(Ld, 15);
        kidx = __builtin_amdgcn_readlane(Li, 15);
    }
}

__global__ __launch_bounds__(256) void knn_grid(
        const float* __restrict__ x, const float* __restrict__ y,
        const int* __restrict__ starts, const float4* __restrict__ ypc,
        const int* __restrict__ aidx,
        int* __restrict__ oidx, float* __restrict__ odist) {
    __shared__ int exp_slots[4][EXPCAP];            // 16 KiB: per-wave candidate buffer
    const int lane = threadIdx.x & 63;
    const int wid  = threadIdx.x >> 6;
    const int n    = blockIdx.x * 4 + wid;          // 5000*4 == 20000 exact
    const float INF = __builtin_inff();

    const float qx = x[3*n], qy = x[3*n+1], qz = x[3*n+2];
    const float qs = (qx*qx + qy*qy) + qz*qz;       // (x**2).sum(1) order
    const int cx = cell_of(qx), cy = cell_of(qy), cz = cell_of(qz);

    float Ld = INF; int Li = 0x7fffffff;
    float kth = INF; int kidx = 0x7fffffff;
    bool filled = false;

    // Lane-parallel segment streaming via LDS EXPANSION: each lane owns one
    // contiguous cell-run [sS, sS+cnt); lanes write candidate addresses to a
    // dense LDS array (no dependent-load binary search), then batches of 64
    // are a single conflict-free ds_read each.
    auto stream_segs = [&](int sS, int cnt) {
        int incl = cnt;
#pragma unroll
        for (int o = 1; o < 64; o <<= 1) {
            int v = __shfl_up(incl, o);
            if (lane >= o) incl += v;
        }
        const int T = __builtin_amdgcn_readlane(incl, 63);
        if (T == 0) return;
        const int off = incl - cnt;                 // exclusive prefix
        for (int base = 0; base < T; base += EXPCAP) {
            const int Tc = min(T - base, EXPCAP);
            int lo = max(off, base), hi = min(off + cnt, base + EXPCAP);
            int cw = hi - lo;                        // <=0 if no overlap
            int wmax = cw;
#pragma unroll
            for (int o = 32; o; o >>= 1) wmax = max(wmax, __shfl_xor(wmax, o));
            int slot0 = lo - base, a0 = sS + (lo - off);
            for (int j = 0; j < wmax; ++j)
                if (j < cw) exp_slots[wid][slot0 + j] = a0 + j;
            asm volatile("s_waitcnt lgkmcnt(0)" ::: "memory");
            for (int b = 0; b < Tc; b += 64) {
                int pos = b + lane; bool val = pos < Tc;
                int rp = val ? pos : 0;
                int a  = exp_slots[wid][rp];
                float4 av = ypc[a];
                int    ai = aidx[a];
                float dot = (qx * av.x + qy * av.y) + qz * av.z;
                float d2  = (qs - 2.f * dot) + av.w;   // same algebra as reference
                if (!val) { d2 = INF; ai = 0x7fffffff; }
                topk_process(d2, ai, lane, Ld, Li, kth, kidx, filled);
            }
        }
    };

    // ---- rings 0..1: 27 single-cell segments, one per lane ----
    {
        int sS = 0, cnt = 0;
        if (lane < 27) {
            int dx = lane % 3 - 1, dyv = (lane / 3) % 3 - 1, dzv = lane / 9 - 1;
            int nx = cx + dx, ny = cy + dyv, nz = cz + dzv;
            if (nx >= 0 && nx < GRIDL && ny >= 0 && ny < GRIDL && nz >= 0 && nz < GRIDL) {
                int cid = (nz * GRIDL + ny) * GRIDL + nx;
                sS  = starts[cid];
                cnt = starts[cid + 1] - sS;
            }
        }
        stream_segs(sS, cnt);
    }

    // ---- shells r>=2, lane-parallel segments, while bound cannot prune ----
    int R = 1;
    while (R < GRIDL) {
        float bnd = (float)R * CELL_H - 0.125f;     // margin covers d2 rounding
        if (bnd * bnd > kth) break;                 // wave-uniform (kth uniform)
        const int r  = R + 1;
        const int n1 = 2 * r + 1, m = 2 * r - 1;
        const int C1 = 2 * n1, C2 = 2 * m;
        const int S  = C1 + C2 + 2 * m * m;
        for (int base = 0; base < S; base += 64) {
            int sid = base + lane;
            int sS = 0, cnt = 0;
            if (sid < S) {
                int dy, dz, xlo, xhi;
                if (sid < C1) {                      // caps dz = +-r, full x-row
                    dz = (sid < n1) ? -r : r;
                    dy = (sid - ((sid < n1) ? 0 : n1)) - r;
                    xlo = cx - r; xhi = cx + r;
                } else if (sid < C1 + C2) {          // dy = +-r edges, full x-row
                    int i = sid - C1;
                    dy = (i < m) ? -r : r;
                    dz = (i - ((i < m) ? 0 : m)) - (r - 1);
                    xlo = cx - r; xhi = cx + r;
                } else {                             // interior: single cells x = +-r
                    int i = sid - C1 - C2;
                    int pair = i >> 1, side = i & 1;
                    dz = (pair / m) - (r - 1);
                    dy = (pair % m) - (r - 1);
                    int xx = side ? cx + r : cx - r;
                    xlo = xx; xhi = xx;
                }
                int ny = cy + dy, nz = cz + dz;
                if (ny >= 0 && ny < GRIDL && nz >= 0 && nz < GRIDL) {
                    int xl = max(xlo, 0), xh = min(xhi, GRIDL - 1);
                    if (xl <= xh) {
                        int cid0 = (nz * GRIDL + ny) * GRIDL + xl;
                        sS  = starts[cid0];
                        cnt = starts[cid0 + (xh - xl) + 1] - sS;
                    }
                }
            }
            stream_segs(sS, cnt);
        }
        R = r;
    }

    // ---- epilogue: exact subtract-form dists for winners ----
    if (lane < KNN) {
        int ii = Li;
        float ax = y[3*ii], ay = y[3*ii+1], az = y[3*ii+2];
        float ddx = qx - ax, ddy = qy - ay, ddz = qz - az;
        float dist = (ddx*ddx + ddy*ddy) + ddz*ddz;   // ((x-y)**2).sum(-1) order
        oidx [n * KNN + lane] = ii;
        odist[n * KNN + lane] = dist;
    }
}

// ---------------- per-atom precompute: A[l][i] = feats[i] @ W1[l][64:128] + b1[l] (fp16) ----------------
#define ATOMS_PER_WAVE 8
#define A_GROUPS (M_ATOMS / ATOMS_PER_WAVE)        // 1250
__global__ __launch_bounds__(256) void precompute_A_kernel(
        const float* __restrict__ feats, const float* __restrict__ W1,
        const float* __restrict__ b1, _Float16* __restrict__ A) {
    int wid = threadIdx.x >> 6, lane = threadIdx.x & 63;
    int id = blockIdx.x * 4 + wid;
    if (id >= NLAYERS * A_GROUPS) return;
    int l = id / A_GROUPS, g = id - l * A_GROUPS;
    int base_atom = g * ATOMS_PER_WAVE;

    float f[ATOMS_PER_WAVE];
#pragma unroll
    for (int a = 0; a < ATOMS_PER_WAVE; ++a) f[a] = feats[(base_atom + a) * DAT + lane];

    float a0[ATOMS_PER_WAVE], a1[ATOMS_PER_WAVE], a2[ATOMS_PER_WAVE];
#pragma unroll
    for (int a = 0; a < ATOMS_PER_WAVE; ++a) { a0[a] = 0.f; a1[a] = 0.f; a2[a] = 0.f; }

    const float* Wl = W1 + (size_t)l * HID * HID;
#pragma unroll 4
    for (int d = 0; d < DAT; ++d) {
        const float* row = Wl + (64 + d) * HID;
        float w0 = row[2 * lane];
        float w1 = row[2 * lane + 1];
        float w2 = row[128];
#pragma unroll
        for (int a = 0; a < ATOMS_PER_WAVE; ++a) {
            float s = readlane_f(f[a], d);
            a0[a] += s * w0;
            a1[a] += s * w1;
            a2[a] += s * w2;
        }
    }
    const float* b1l = b1 + l * HID;
    float bb0 = b1l[2 * lane], bb1 = b1l[2 * lane + 1], bb2 = b1l[128];
#pragma unroll
    for (int a = 0; a < ATOMS_PER_WAVE; ++a) {
        _Float16* Ar = A + ((size_t)l * M_ATOMS + base_atom + a) * A_HSTRIDE;
        half2_t hv; hv.x = (_Float16)(a0[a] + bb0); hv.y = (_Float16)(a1[a] + bb1);
        ((half2_t*)Ar)[lane] = hv;
        if (lane == 0) Ar[128] = (_Float16)(a2[a] + bb2);
    }
}

// ---------------- one layer of the MLP + groupnorm ----------------
template<bool FIRST, bool LAST>
__global__ __launch_bounds__(512) void layer_kernel(
        int l,
        const float* __restrict__ W1, const float* __restrict__ W2,
        const float* __restrict__ b2, const float* __restrict__ gnw,
        const float* __restrict__ gnb, const _Float16* __restrict__ A,
        const int* __restrict__ oidx, const float* __restrict__ odist,
        float* __restrict__ pe_buf, float* __restrict__ out) {
    __shared__ float2 w1s[64 * 64];   // [d][lane] = (W1[d][2l], W1[d][2l+1])   32KB
    __shared__ float2 w2s[64 * 64];   // [j][lane] = (W2[2j][l..], W2[2j+1][..]) 32KB
    const int wave = threadIdx.x >> 6, lane = threadIdx.x & 63;

    const float* Wl  = W1 + (size_t)l * HID * HID;
    const float* W2l = W2 + (size_t)l * HID * DAT;
    for (int d = wave; d < 64; d += 8) {
        w1s[d * 64 + lane] = make_float2(Wl[d * HID + 2 * lane], Wl[d * HID + 2 * lane + 1]);
        w2s[d * 64 + lane] = make_float2(W2l[(2 * d) * DAT + lane], W2l[(2 * d + 1) * DAT + lane]);
    }
    const float wl0 = Wl[128 * HID + 2 * lane], wl1 = Wl[128 * HID + 2 * lane + 1];
    const float wl2 = Wl[128 * HID + 128];
    const float w1c = Wl[lane * HID + 128];
    const float w2c = W2l[128 * DAT + lane];
    const float b2v = 16.f * b2[l * DAT + lane];
    const float gw  = gnw[l * DAT + lane], gb = gnb[l * DAT + lane];
    __syncthreads();

    float fp0 = 0.f, fp1 = 0.f, fp2 = 0.f;
    if (FIRST) {
#pragma unroll 8
        for (int d = 0; d < 64; ++d) {
            float2 w2v = w1s[d * 64 + lane];
            fp0 += w2v.x; fp1 += w2v.y;
        }
        float v = w1c;
        v += __shfl_xor(v, 1);  v += __shfl_xor(v, 2);  v += __shfl_xor(v, 4);
        v += __shfl_xor(v, 8);  v += __shfl_xor(v, 16); v += __shfl_xor(v, 32);
        fp2 = v;
    }

    const _Float16* Al = A + (size_t)l * M_ATOMS * A_HSTRIDE;

#pragma unroll
    for (int pt = 0; pt < PTS_L; ++pt) {
        const int n = (blockIdx.x * 8 + wave) * PTS_L + pt;   // 1250*8*2 == 20000

        float pe = FIRST ? 1.0f : pe_buf[n * DAT + lane];
        int   ikl = 0; float dkl = 0.f;
        if (lane < KNN) { ikl = oidx[n * KNN + lane]; dkl = odist[n * KNN + lane]; }
        int ii[KNN]; float dd[KNN];
#pragma unroll
        for (int k = 0; k < KNN; ++k) {
            ii[k] = __builtin_amdgcn_readlane(ikl, k);
            dd[k] = readlane_f(dkl, k);
        }

        half2_t Av01[KNN]; _Float16 Av2[KNN];
#pragma unroll
        for (int k = 0; k < KNN; ++k) {
            const _Float16* Ar = Al + (size_t)ii[k] * A_HSTRIDE;
            Av01[k] = ((const half2_t*)Ar)[lane];
            Av2[k]  = Ar[128];
        }

        float p0, p1, p2;
        if (FIRST) { p0 = fp0; p1 = fp1; p2 = fp2; }
        else {
            p0 = 0.f; p1 = 0.f;
#pragma unroll 8
            for (int d = 0; d < 64; ++d) {
                float s = readlane_f(pe, d);
                float2 w2v = w1s[d * 64 + lane];
                p0 += s * w2v.x;
                p1 += s * w2v.y;
            }
            float v = pe * w1c;
            v += __shfl_xor(v, 1);  v += __shfl_xor(v, 2);  v += __shfl_xor(v, 4);
            v += __shfl_xor(v, 8);  v += __shfl_xor(v, 16); v += __shfl_xor(v, 32);
            p2 = v;
        }

        float hs0 = 0.f, hs1 = 0.f, hs2 = 0.f;
#pragma unroll
        for (int k = 0; k < KNN; ++k) {
            float A0 = (float)Av01[k].x, A1 = (float)Av01[k].y, A2 = (float)Av2[k];
            float h0 = p0 + A0 + dd[k] * wl0; h0 = h0 >= 0.f ? h0 : 0.2f * h0; hs0 += h0;
            float h1 = p1 + A1 + dd[k] * wl1; h1 = h1 >= 0.f ? h1 : 0.2f * h1; hs1 += h1;
            float h2 = p2 + A2 + dd[k] * wl2; h2 = h2 >= 0.f ? h2 : 0.2f * h2; hs2 += h2;
        }

        float m0 = 0.f, m1 = 0.f;
#pragma unroll 8
        for (int j = 0; j < 64; j += 2) {
            float a0 = readlane_f(hs0, j),     a1 = readlane_f(hs1, j);
            float b0 = readlane_f(hs0, j + 1), b1 = readlane_f(hs1, j + 1);
            float2 wa = w2s[j * 64 + lane];
            float2 wb = w2s[(j + 1) * 64 + lane];
            m0 += a0 * wa.x; m0 += a1 * wa.y;
            m1 += b0 * wb.x; m1 += b1 * wb.y;
        }
        float m = (m0 + m1) + hs2 * w2c + b2v;

        float s1 = m;
        s1 += __shfl_xor(s1, 1);  s1 += __shfl_xor(s1, 2);  s1 += __shfl_xor(s1, 4);
        s1 += __shfl_xor(s1, 8);  s1 += __shfl_xor(s1, 16);
        float mu = s1 * (1.f / 32.f);
        float dm = m - mu;
        float s2 = dm * dm;
        s2 += __shfl_xor(s2, 1);  s2 += __shfl_xor(s2, 2);  s2 += __shfl_xor(s2, 4);
        s2 += __shfl_xor(s2, 8);  s2 += __shfl_xor(s2, 16);
        float var = s2 * (1.f / 32.f);
        float g = dm * (1.f / sqrtf(var + 1e-5f)) * gw + gb;
        pe += (g >= 0.f) ? g : 0.2f * g;

        if (LAST) out[n * DAT + lane] = pe;
        else      pe_buf[n * DAT + lane] = pe;
    }
}

// ---------------- launch ----------------
extern "C" void kernel_launch(void* const* d_in, const int* in_sizes, int n_in,
                              void* d_out, int out_size, void* d_ws, size_t ws_size,
                              hipStream_t stream) {
    const float* x     = (const float*)d_in[0];
    const float* y     = (const float*)d_in[1];
    const float* feats = (const float*)d_in[2];
    const float* W1    = (const float*)d_in[3];
    const float* b1    = (const float*)d_in[4];
    const float* W2    = (const float*)d_in[5];
    const float* b2    = (const float*)d_in[6];
    const float* gnw   = (const float*)d_in[7];
    const float* gnb   = (const float*)d_in[8];
    float* out = (float*)d_out;

    char* ws = (char*)d_ws;
    float4*    ypc   = (float4*)  ws;                        // 160,000 B
    int*       oidx  = (int*)    (ws + 160000);              // 1,280,000 B
    float*     odist = (float*)  (ws + 1440000);             // 1,280,000 B
    _Float16*  A     = (_Float16*)(ws + 2720000);            // 7,920,000 B
    float*     pe_buf= (float*)  (ws + 10640000);            // 5,120,000 B
    //   grid scratch ALIASED into pe_buf region (dead before layer 0 writes):
    int*       starts= (int*)    (ws + 10640000);            // (110592+1)*4 = 442,372
    int*       cursor= (int*)    (ws + 11082376);            // counts -> cursor, 442,368
    int*       bsum  = (int*)    (ws + 11524744);            // 432*4
    int*       boff  = (int*)    (ws + 11526472);            // 432*4
    int*       aidx  = (int*)    (ws + 15760000);            // 40,000 B
    // total 15.8 MB of ws

    grid_zero   <<<dim3(SCAN_NBLK), dim3(256), 0, stream>>>(cursor);
    grid_count  <<<dim3((M_ATOMS + 255) / 256), dim3(256), 0, stream>>>(y, cursor);
    scanA       <<<dim3(SCAN_NBLK), dim3(256), 0, stream>>>(cursor, bsum);
    scanB       <<<dim3(1), dim3(512), 0, stream>>>(bsum, boff, starts);
    scanC       <<<dim3(SCAN_NBLK), dim3(256), 0, stream>>>(cursor, boff, starts);
    grid_scatter<<<dim3((M_ATOMS + 255) / 256), dim3(256), 0, stream>>>(y, cursor, ypc, aidx);
    knn_grid    <<<dim3(N_PTS / 4), dim3(256), 0, stream>>>(x, y, starts, ypc, aidx, oidx, odist);

    precompute_A_kernel<<<dim3((NLAYERS * A_GROUPS + 3) / 4), dim3(256), 0, stream>>>(feats, W1, b1, A);
    layer_kernel<true,  false><<<dim3(1250), dim3(512), 0, stream>>>(0, W1, W2, b2, gnw, gnb, A, oidx, odist, pe_buf, out);
    layer_kernel<false, false><<<dim3(1250), dim3(512), 0, stream>>>(1, W1, W2, b2, gnw, gnb, A, oidx, odist, pe_buf, out);
    layer_kernel<false, true ><<<dim3(1250), dim3(512), 0, stream>>>(2, W1, W2, b2, gnw, gnb, A, oidx, odist, pe_buf, out);
}

// Round 10
// 240.591 us; speedup vs baseline: 1.1506x; 1.1506x over previous
//
#include <hip/hip_runtime.h>

#define N_PTS   20000
#define M_ATOMS 10000
#define DAT     64
#define HID     129
#define KNN     16
#define NLAYERS 3

#define A_HSTRIDE  132        // A row stride in HALVES (264 B, 8B-aligned)

#define GRIDL   24
#define NCELL   (GRIDL*GRIDL*GRIDL)   // 13824
#define CELL_H  4.0f
#define INV_H   0.25f
#define GORIG   (-48.0f)

typedef _Float16 half2_t __attribute__((ext_vector_type(2)));

__device__ __forceinline__ float readlane_f(float v, int l) {
    return __int_as_float(__builtin_amdgcn_readlane(__float_as_int(v), l));
}
__device__ __forceinline__ int cell_of(float v) {
    int c = (int)floorf((v - GORIG) * INV_H);
    return c < 0 ? 0 : (c > GRIDL - 1 ? GRIDL - 1 : c);
}

// ================= grid build (h=4, round-8 verified) =================
__global__ void grid_zero(int* __restrict__ counts) {
    int i = blockIdx.x * 256 + threadIdx.x;
    if (i <= NCELL) counts[i] = 0;
}

__global__ void grid_count(const float* __restrict__ y, int* __restrict__ counts,
                           int* __restrict__ acell) {
    int i = blockIdx.x * 256 + threadIdx.x;
    if (i >= M_ATOMS) return;
    float a = y[3*i], b = y[3*i+1], c = y[3*i+2];
    int cid = (cell_of(c) * GRIDL + cell_of(b)) * GRIDL + cell_of(a);
    acell[i] = cid;
    atomicAdd(&counts[cid], 1);
}

__global__ __launch_bounds__(1024) void grid_scan(const int* __restrict__ counts,
        int* __restrict__ starts, int* __restrict__ cursor) {
    __shared__ int part[1024];
    const int t = threadIdx.x;
    const int base = t * 14;                       // 1024*14 = 14336 >= 13824
    int loc[14]; int sum = 0;
#pragma unroll
    for (int i = 0; i < 14; ++i) {
        int idx = base + i;
        int c = (idx < NCELL) ? counts[idx] : 0;
        loc[i] = sum; sum += c;
    }
    part[t] = sum;
    for (int o = 1; o < 1024; o <<= 1) {
        __syncthreads();
        int v = (t >= o) ? part[t - o] : 0;
        __syncthreads();
        part[t] += v;
    }
    __syncthreads();
    int prev = (t > 0) ? part[t - 1] : 0;
#pragma unroll
    for (int i = 0; i < 14; ++i) {
        int idx = base + i;
        if (idx < NCELL) { int s = prev + loc[i]; starts[idx] = s; cursor[idx] = s; }
    }
    if (t == 1023) starts[NCELL] = part[1023];
}

__global__ void grid_scatter(const float* __restrict__ y, const int* __restrict__ acell,
                             int* __restrict__ cursor, float4* __restrict__ ypc,
                             int* __restrict__ aidx) {
    int i = blockIdx.x * 256 + threadIdx.x;
    if (i >= M_ATOMS) return;
    int cid = acell[i];
    int pos = atomicAdd(&cursor[cid], 1);
    float a = y[3*i], b = y[3*i+1], c = y[3*i+2];
    ypc[pos]  = make_float4(a, b, c, (a*a + b*b) + c*c);   // (y**2).sum(1) order
    aidx[pos] = i;
}

// ================= grid kNN query =================
// Top-16 in lanes 0..15 sorted ascending by (d2, idx) lexicographic ==
// jax.lax.top_k tie semantics; deterministic regardless of traversal order.
__device__ __forceinline__ void topk_process(float d2, int ai, int lane,
        float& Ld, int& Li, float& kth, int& kidx, bool& filled) {
    const float INF = __builtin_inff();
    if (!filled) {                                  // bitonic-sort fill (wave-uniform)
        float v = d2; int ix = ai;
#pragma unroll
        for (int k = 2; k <= 64; k <<= 1)
#pragma unroll
            for (int j = k >> 1; j > 0; j >>= 1) {
                float ov = __shfl_xor(v, j);
                int   oi = __shfl_xor(ix, j);
                bool keepmin = (((lane & k) == 0) == ((lane & j) == 0));
                bool oless   = (ov < v) || (ov == v && oi < ix);
                bool take    = (keepmin == oless);
                v  = take ? ov : v;
                ix = take ? oi : ix;
            }
        Ld = (lane < KNN) ? v : INF;
        Li = (lane < KNN) ? ix : 0x7fffffff;
        kth  = readlane_f(v, 15);
        kidx = __builtin_amdgcn_readlane(ix, 15);
        filled = true;
        return;
    }
    bool adm = (d2 < kth) || (d2 == kth && ai < kidx);
    unsigned long long cand = __ballot(adm);
    if (cand) {
        do {
            int src = __builtin_ctzll(cand);
            cand &= cand - 1;
            float v  = readlane_f(d2, src);
            int   mi = __builtin_amdgcn_readlane(ai, src);
            bool pred = (Ld > v) || (Ld == v && Li > mi);   // lexicographic
            unsigned long long bal = __ballot(pred);
            int ins = __builtin_ctzll(bal);
            float pd = __shfl_up(Ld, 1);
            int   pi = __shfl_up(Li, 1);
            bool atins = (lane == ins);
            float tv = atins ? v  : pd;
            int   ti = atins ? mi : pi;
            Ld = pred ? tv : Ld;
            Li = pred ? ti : Li;
        } while (cand);
        kth  = readlane_f(Ld, 15);
        kidx = __builtin_amdgcn_readlane(Li, 15);
    }
}

__global__ __launch_bounds__(256) void knn_grid(
        const float* __restrict__ x, const float* __restrict__ y,
        const int* __restrict__ starts, const float4* __restrict__ ypc,
        const int* __restrict__ aidx,
        int* __restrict__ oidx, float* __restrict__ odist) {
    __shared__ int s_start[4][64];
    __shared__ int s_off[4][64];
    const int lane = threadIdx.x & 63;
    const int wid  = threadIdx.x >> 6;
    const int n    = blockIdx.x * 4 + wid;          // 5000*4 == 20000 exact
    const float INF = __builtin_inff();

    const float qx = x[3*n], qy = x[3*n+1], qz = x[3*n+2];
    const float qs = (qx*qx + qy*qy) + qz*qz;       // (x**2).sum(1) order
    const int cx = cell_of(qx), cy = cell_of(qy), cz = cell_of(qz);

    float Ld = INF; int Li = 0x7fffffff;
    float kth = INF; int kidx = 0x7fffffff;
    bool filled = false;

    // ---- rings 0..1: 9 contiguous x-runs, iterated SERIALLY (no LDS, no
    // binary search; contiguous coalesced batches; center row first to seed
    // kth with the densest nearby candidates) ----
    {
        int sS = 0, cnt = 0;
        if (lane < 9) {
            int dyv = lane % 3 - 1, dzv = lane / 3 - 1;
            int ny = cy + dyv, nz = cz + dzv;
            if (ny >= 0 && ny < GRIDL && nz >= 0 && nz < GRIDL) {
                int xl = max(cx - 1, 0), xh = min(cx + 1, GRIDL - 1);
                int cid0 = (nz * GRIDL + ny) * GRIDL + xl;
                sS  = starts[cid0];
                cnt = starts[cid0 + (xh - xl) + 1] - sS;
            }
        }
#pragma unroll
        for (int si = 0; si < 9; ++si) {
            const int s = (si == 0) ? 4 : (si <= 4 ? si - 1 : si);  // {4,0,1,2,3,5,6,7,8}
            const int ss = __builtin_amdgcn_readlane(sS, s);
            const int cc = __builtin_amdgcn_readlane(cnt, s);
            for (int b = 0; b < cc; b += 64) {
                int pos = b + lane; bool val = pos < cc;
                int a = val ? (ss + pos) : ss;
                float4 av = ypc[a];
                int    ai = aidx[a];
                float dot = (qx * av.x + qy * av.y) + qz * av.z;
                float d2  = (qs - 2.f * dot) + av.w;   // same algebra as reference
                if (!val) { d2 = INF; ai = 0x7fffffff; }
                topk_process(d2, ai, lane, Ld, Li, kth, kidx, filled);
            }
        }
    }

    // ---- shells r>=2 (rare): lane-parallel segments + binary search ----
    int R = 1;
    while (R < GRIDL) {
        float bnd = (float)R * CELL_H - 0.125f;     // margin covers d2 rounding
        if (bnd * bnd > kth) break;                 // wave-uniform (kth uniform)
        const int r  = R + 1;
        const int n1 = 2 * r + 1, m = 2 * r - 1;
        const int C1 = 2 * n1, C2 = 2 * m;
        const int S  = C1 + C2 + 2 * m * m;
        for (int base = 0; base < S; base += 64) {
            int sid = base + lane;
            int sS = 0, cnt = 0;
            if (sid < S) {
                int dy, dz, xlo, xhi;
                if (sid < C1) {                      // caps dz = +-r, full x-row
                    dz = (sid < n1) ? -r : r;
                    dy = (sid - ((sid < n1) ? 0 : n1)) - r;
                    xlo = cx - r; xhi = cx + r;
                } else if (sid < C1 + C2) {          // dy = +-r edges, full x-row
                    int i = sid - C1;
                    dy = (i < m) ? -r : r;
                    dz = (i - ((i < m) ? 0 : m)) - (r - 1);
                    xlo = cx - r; xhi = cx + r;
                } else {                             // interior: single cells x = +-r
                    int i = sid - C1 - C2;
                    int pair = i >> 1, side = i & 1;
                    dz = (pair / m) - (r - 1);
                    dy = (pair % m) - (r - 1);
                    int xx = side ? cx + r : cx - r;
                    xlo = xx; xhi = xx;
                }
                int ny = cy + dy, nz = cz + dz;
                if (ny >= 0 && ny < GRIDL && nz >= 0 && nz < GRIDL) {
                    int xl = max(xlo, 0), xh = min(xhi, GRIDL - 1);
                    if (xl <= xh) {
                        int cid0 = (nz * GRIDL + ny) * GRIDL + xl;
                        sS  = starts[cid0];
                        cnt = starts[cid0 + (xh - xl) + 1] - sS;
                    }
                }
            }
            // prefix-scan + binary-search streaming (round-8 verified path)
            int incl = cnt;
#pragma unroll
            for (int o = 1; o < 64; o <<= 1) {
                int v = __shfl_up(incl, o);
                if (lane >= o) incl += v;
            }
            const int T = __builtin_amdgcn_readlane(incl, 63);
            if (T == 0) continue;
            s_start[wid][lane] = sS;
            s_off[wid][lane]   = incl - cnt;
            for (int b = 0; b < T; b += 64) {
                int pos = b + lane; bool val = pos < T;
                int c = 0;
                c += (s_off[wid][c + 32] <= pos) ? 32 : 0;
                c += (s_off[wid][c + 16] <= pos) ? 16 : 0;
                c += (s_off[wid][c + 8]  <= pos) ? 8  : 0;
                c += (s_off[wid][c + 4]  <= pos) ? 4  : 0;
                c += (s_off[wid][c + 2]  <= pos) ? 2  : 0;
                c += (s_off[wid][c + 1]  <= pos) ? 1  : 0;
                int a = s_start[wid][c] + (pos - s_off[wid][c]);
                a = val ? a : 0;
                float4 av = ypc[a];
                int    ai = aidx[a];
                float dot = (qx * av.x + qy * av.y) + qz * av.z;
                float d2  = (qs - 2.f * dot) + av.w;
                if (!val) { d2 = INF; ai = 0x7fffffff; }
                topk_process(d2, ai, lane, Ld, Li, kth, kidx, filled);
            }
        }
        R = r;
    }

    // ---- epilogue: exact subtract-form dists for winners ----
    if (lane < KNN) {
        int ii = Li;
        float ax = y[3*ii], ay = y[3*ii+1], az = y[3*ii+2];
        float ddx = qx - ax, ddy = qy - ay, ddz = qz - az;
        float dist = (ddx*ddx + ddy*ddy) + ddz*ddz;   // ((x-y)**2).sum(-1) order
        oidx [n * KNN + lane] = ii;
        odist[n * KNN + lane] = dist;
    }
}

// ---------------- per-atom precompute: A[l][i] = feats[i] @ W1[l][64:128] + b1[l] (fp16) ----------------
#define ATOMS_PER_WAVE 8
#define A_GROUPS (M_ATOMS / ATOMS_PER_WAVE)        // 1250
__global__ __launch_bounds__(256) void precompute_A_kernel(
        const float* __restrict__ feats, const float* __restrict__ W1,
        const float* __restrict__ b1, _Float16* __restrict__ A) {
    int wid = threadIdx.x >> 6, lane = threadIdx.x & 63;
    int id = blockIdx.x * 4 + wid;
    if (id >= NLAYERS * A_GROUPS) return;
    int l = id / A_GROUPS, g = id - l * A_GROUPS;
    int base_atom = g * ATOMS_PER_WAVE;

    float f[ATOMS_PER_WAVE];
#pragma unroll
    for (int a = 0; a < ATOMS_PER_WAVE; ++a) f[a] = feats[(base_atom + a) * DAT + lane];

    float a0[ATOMS_PER_WAVE], a1[ATOMS_PER_WAVE], a2[ATOMS_PER_WAVE];
#pragma unroll
    for (int a = 0; a < ATOMS_PER_WAVE; ++a) { a0[a] = 0.f; a1[a] = 0.f; a2[a] = 0.f; }

    const float* Wl = W1 + (size_t)l * HID * HID;
#pragma unroll 4
    for (int d = 0; d < DAT; ++d) {
        const float* row = Wl + (64 + d) * HID;
        float w0 = row[2 * lane];
        float w1 = row[2 * lane + 1];
        float w2 = row[128];
#pragma unroll
        for (int a = 0; a < ATOMS_PER_WAVE; ++a) {
            float s = readlane_f(f[a], d);
            a0[a] += s * w0;
            a1[a] += s * w1;
            a2[a] += s * w2;
        }
    }
    const float* b1l = b1 + l * HID;
    float bb0 = b1l[2 * lane], bb1 = b1l[2 * lane + 1], bb2 = b1l[128];
#pragma unroll
    for (int a = 0; a < ATOMS_PER_WAVE; ++a) {
        _Float16* Ar = A + ((size_t)l * M_ATOMS + base_atom + a) * A_HSTRIDE;
        half2_t hv; hv.x = (_Float16)(a0[a] + bb0); hv.y = (_Float16)(a1[a] + bb1);
        ((half2_t*)Ar)[lane] = hv;
        if (lane == 0) Ar[128] = (_Float16)(a2[a] + bb2);
    }
}

// ---------------- fused 3-layer MLP + groupnorm ----------------
// Layers are point-local -> fuse all 3 in one kernel: no pe_buf round-trip,
// oidx/odist loaded once, A-gathers issued before the staging barrier so
// their latency hides under the 64KB weight staging.
__global__ __launch_bounds__(512) void mlp_fused(
        const float* __restrict__ W1, const float* __restrict__ W2,
        const float* __restrict__ b2, const float* __restrict__ gnw,
        const float* __restrict__ gnb, const _Float16* __restrict__ A,
        const int* __restrict__ oidx, const float* __restrict__ odist,
        float* __restrict__ out) {
    __shared__ float2 w1s[64 * 64];   // [d][lane] = (W1[d][2l], W1[d][2l+1])   32KB
    __shared__ float2 w2s[64 * 64];   // [j][lane] = (W2[2j][l..], W2[2j+1][..]) 32KB
    const int wave = threadIdx.x >> 6, lane = threadIdx.x & 63;
    const int n0 = (blockIdx.x * 8 + wave) * 2;     // 1250*8*2 == 20000

    int ikl0 = 0, ikl1 = 0; float dkl0 = 0.f, dkl1 = 0.f;
    if (lane < KNN) {
        ikl0 = oidx[n0 * KNN + lane];       dkl0 = odist[n0 * KNN + lane];
        ikl1 = oidx[(n0 + 1) * KNN + lane]; dkl1 = odist[(n0 + 1) * KNN + lane];
    }
    float pe0 = 1.f, pe1 = 1.f;

    for (int l = 0; l < NLAYERS; ++l) {
        if (l) __syncthreads();                    // prev layer done reading LDS
        const float* Wl  = W1 + (size_t)l * HID * HID;
        const float* W2l = W2 + (size_t)l * HID * DAT;
        for (int d = wave; d < 64; d += 8) {
            w1s[d * 64 + lane] = make_float2(Wl[d * HID + 2 * lane], Wl[d * HID + 2 * lane + 1]);
            w2s[d * 64 + lane] = make_float2(W2l[(2 * d) * DAT + lane], W2l[(2 * d + 1) * DAT + lane]);
        }
        const float wl0 = Wl[128 * HID + 2 * lane], wl1 = Wl[128 * HID + 2 * lane + 1];
        const float wl2 = Wl[128 * HID + 128];
        const float w1c = Wl[lane * HID + 128];
        const float w2c = W2l[128 * DAT + lane];
        const float b2v = 16.f * b2[l * DAT + lane];
        const float gw  = gnw[l * DAT + lane], gb = gnb[l * DAT + lane];

        // issue gathered-A loads BEFORE the staging barrier (hidden under it)
        const _Float16* Al = A + (size_t)l * M_ATOMS * A_HSTRIDE;
        half2_t Av0[KNN], Av1[KNN];
#pragma unroll
        for (int k = 0; k < KNN; ++k) {
            int i0 = __builtin_amdgcn_readlane(ikl0, k);
            int i1 = __builtin_amdgcn_readlane(ikl1, k);
            Av0[k] = ((const half2_t*)(Al + (size_t)i0 * A_HSTRIDE))[lane];
            Av1[k] = ((const half2_t*)(Al + (size_t)i1 * A_HSTRIDE))[lane];
        }
        float A2l0 = 0.f, A2l1 = 0.f;              // lane k holds channel-128 of neighbor k
        if (lane < KNN) {
            A2l0 = (float)Al[(size_t)ikl0 * A_HSTRIDE + 128];
            A2l1 = (float)Al[(size_t)ikl1 * A_HSTRIDE + 128];
        }
        __syncthreads();                           // weights staged

        // layer 0: pe == 1 -> p-vector identical for all points
        float fpa = 0.f, fpb = 0.f, fpc = 0.f;
        if (l == 0) {
#pragma unroll 8
            for (int d = 0; d < 64; ++d) {
                float2 w = w1s[d * 64 + lane];
                fpa += w.x; fpb += w.y;
            }
            float v = w1c;
            v += __shfl_xor(v, 1);  v += __shfl_xor(v, 2);  v += __shfl_xor(v, 4);
            v += __shfl_xor(v, 8);  v += __shfl_xor(v, 16); v += __shfl_xor(v, 32);
            fpc = v;
        }

        auto point = [&](float& pe, const half2_t* Av, float A2l, float dkl) {
            float p0, p1, p2;
            if (l == 0) { p0 = fpa; p1 = fpb; p2 = fpc; }
            else {
                p0 = 0.f; p1 = 0.f;
#pragma unroll 8
                for (int d = 0; d < 64; ++d) {
                    float s = readlane_f(pe, d);
                    float2 w = w1s[d * 64 + lane];
                    p0 += s * w.x;
                    p1 += s * w.y;
                }
                float v = pe * w1c;                // dot(pe, W1[:,128]) via reduce
                v += __shfl_xor(v, 1);  v += __shfl_xor(v, 2);  v += __shfl_xor(v, 4);
                v += __shfl_xor(v, 8);  v += __shfl_xor(v, 16); v += __shfl_xor(v, 32);
                p2 = v;
            }

            // hsum = sum_k leaky(p + A[idx_k] + dist_k * wl)
            float hs0 = 0.f, hs1 = 0.f, hs2 = 0.f;
#pragma unroll
            for (int k = 0; k < KNN; ++k) {
                float ddk = readlane_f(dkl, k);
                float A2  = readlane_f(A2l, k);
                float A0 = (float)Av[k].x, A1 = (float)Av[k].y;
                float h0 = p0 + A0 + ddk * wl0; h0 = h0 >= 0.f ? h0 : 0.2f * h0; hs0 += h0;
                float h1 = p1 + A1 + ddk * wl1; h1 = h1 >= 0.f ? h1 : 0.2f * h1; hs1 += h1;
                float h2 = p2 + A2 + ddk * wl2; h2 = h2 >= 0.f ? h2 : 0.2f * h2; hs2 += h2;
            }

            // msg = hsum @ W2[l] + K*b2[l]
            float m0 = 0.f, m1 = 0.f;
#pragma unroll 8
            for (int j = 0; j < 64; j += 2) {
                float a0 = readlane_f(hs0, j),     a1 = readlane_f(hs1, j);
                float b0 = readlane_f(hs0, j + 1), b1 = readlane_f(hs1, j + 1);
                float2 wa = w2s[j * 64 + lane];
                float2 wb = w2s[(j + 1) * 64 + lane];
                m0 += a0 * wa.x; m0 += a1 * wa.y;
                m1 += b0 * wb.x; m1 += b1 * wb.y;
            }
            float m = (m0 + m1) + hs2 * w2c + b2v;

            // GroupNorm(2 groups of 32 channels) within aligned 32-lane halves
            float s1 = m;
            s1 += __shfl_xor(s1, 1);  s1 += __shfl_xor(s1, 2);  s1 += __shfl_xor(s1, 4);
            s1 += __shfl_xor(s1, 8);  s1 += __shfl_xor(s1, 16);
            float mu = s1 * (1.f / 32.f);
            float dm = m - mu;
            float s2 = dm * dm;
            s2 += __shfl_xor(s2, 1);  s2 += __shfl_xor(s2, 2);  s2 += __shfl_xor(s2, 4);
            s2 += __shfl_xor(s2, 8);  s2 += __shfl_xor(s2, 16);
            float var = s2 * (1.f / 32.f);
            float g = dm * (1.f / sqrtf(var + 1e-5f)) * gw + gb;
            pe += (g >= 0.f) ? g : 0.2f * g;       // leaky, residual add
        };
        point(pe0, Av0, A2l0, dkl0);
        point(pe1, Av1, A2l1, dkl1);
    }

    out[n0 * DAT + lane]       = pe0;
    out[(n0 + 1) * DAT + lane] = pe1;
}

// ---------------- launch ----------------
extern "C" void kernel_launch(void* const* d_in, const int* in_sizes, int n_in,
                              void* d_out, int out_size, void* d_ws, size_t ws_size,
                              hipStream_t stream) {
    const float* x     = (const float*)d_in[0];
    const float* y     = (const float*)d_in[1];
    const float* feats = (const float*)d_in[2];
    const float* W1    = (const float*)d_in[3];
    const float* b1    = (const float*)d_in[4];
    const float* W2    = (const float*)d_in[5];
    const float* b2    = (const float*)d_in[6];
    const float* gnw   = (const float*)d_in[7];
    const float* gnb   = (const float*)d_in[8];
    float* out = (float*)d_out;

    char* ws = (char*)d_ws;
    float4*    ypc   = (float4*)  ws;                        // 160,000 B
    int*       oidx  = (int*)    (ws + 160000);              // 1,280,000 B
    float*     odist = (float*)  (ws + 1440000);             // 1,280,000 B
    _Float16*  A     = (_Float16*)(ws + 2720000);            // 7,920,000 B
    int*       starts= (int*)    (ws + 10640000);            // (13824+1)*4
    int*       cursor= (int*)    (ws + 10700000);            // 13824*4
    int*       counts= (int*)    (ws + 10760000);            // (13824+1)*4
    int*       acell = (int*)    (ws + 10820000);            // 10000*4
    int*       aidx  = (int*)    (ws + 10860000);            // 10000*4
    // total ~10.9 MB of ws

    grid_zero   <<<dim3((NCELL + 256) / 256), dim3(256), 0, stream>>>(counts);
    grid_count  <<<dim3((M_ATOMS + 255) / 256), dim3(256), 0, stream>>>(y, counts, acell);
    grid_scan   <<<dim3(1), dim3(1024), 0, stream>>>(counts, starts, cursor);
    grid_scatter<<<dim3((M_ATOMS + 255) / 256), dim3(256), 0, stream>>>(y, acell, cursor, ypc, aidx);
    knn_grid    <<<dim3(N_PTS / 4), dim3(256), 0, stream>>>(x, y, starts, ypc, aidx, oidx, odist);

    precompute_A_kernel<<<dim3((NLAYERS * A_GROUPS + 3) / 4), dim3(256), 0, stream>>>(feats, W1, b1, A);
    mlp_fused   <<<dim3(1250), dim3(512), 0, stream>>>(W1, W2, b2, gnw, gnb, A, oidx, odist, out);
}

// Round 11
// 240.463 us; speedup vs baseline: 1.1513x; 1.0005x over previous
//
#include <hip/hip_runtime.h>

#define N_PTS   20000
#define M_ATOMS 10000
#define DAT     64
#define HID     129
#define KNN     16
#define NLAYERS 3

#define A_HSTRIDE  132        // A row stride in HALVES (264 B, 8B-aligned)

#define GRIDL   24
#define NCELL   (GRIDL*GRIDL*GRIDL)   // 13824
#define CELL_H  4.0f
#define INV_H   0.25f
#define GORIG   (-48.0f)

#define KNN_NBLK   (N_PTS / 4)                    // 5000
#define A_GROUPS   (M_ATOMS / 8)                  // 1250 (8 atoms/wave)
#define PRE_NBLK   ((NLAYERS * A_GROUPS + 3) / 4) // 938

typedef _Float16 half2_t __attribute__((ext_vector_type(2)));

__device__ __forceinline__ float readlane_f(float v, int l) {
    return __int_as_float(__builtin_amdgcn_readlane(__float_as_int(v), l));
}
__device__ __forceinline__ int cell_of(float v) {
    int c = (int)floorf((v - GORIG) * INV_H);
    return c < 0 ? 0 : (c > GRIDL - 1 ? GRIDL - 1 : c);
}

// ================= grid build (h=4) =================
__global__ void grid_zero(int* __restrict__ counts) {
    int i = blockIdx.x * 256 + threadIdx.x;
    if (i <= NCELL) counts[i] = 0;
}

__global__ void grid_count(const float* __restrict__ y, int* __restrict__ counts,
                           int* __restrict__ acell) {
    int i = blockIdx.x * 256 + threadIdx.x;
    if (i >= M_ATOMS) return;
    float a = y[3*i], b = y[3*i+1], c = y[3*i+2];
    int cid = (cell_of(c) * GRIDL + cell_of(b)) * GRIDL + cell_of(a);
    acell[i] = cid;
    atomicAdd(&counts[cid], 1);
}

__global__ __launch_bounds__(1024) void grid_scan(const int* __restrict__ counts,
        int* __restrict__ starts, int* __restrict__ cursor) {
    __shared__ int part[1024];
    const int t = threadIdx.x;
    const int base = t * 14;                       // 1024*14 = 14336 >= 13824
    int loc[14]; int sum = 0;
#pragma unroll
    for (int i = 0; i < 14; ++i) {
        int idx = base + i;
        int c = (idx < NCELL) ? counts[idx] : 0;
        loc[i] = sum; sum += c;
    }
    part[t] = sum;
    for (int o = 1; o < 1024; o <<= 1) {
        __syncthreads();
        int v = (t >= o) ? part[t - o] : 0;
        __syncthreads();
        part[t] += v;
    }
    __syncthreads();
    int prev = (t > 0) ? part[t - 1] : 0;
#pragma unroll
    for (int i = 0; i < 14; ++i) {
        int idx = base + i;
        if (idx < NCELL) { int s = prev + loc[i]; starts[idx] = s; cursor[idx] = s; }
    }
    if (t == 1023) starts[NCELL] = part[1023];
}

__global__ void grid_scatter(const float* __restrict__ y, const int* __restrict__ acell,
                             int* __restrict__ cursor, float4* __restrict__ ypc,
                             int* __restrict__ aidx) {
    int i = blockIdx.x * 256 + threadIdx.x;
    if (i >= M_ATOMS) return;
    int cid = acell[i];
    int pos = atomicAdd(&cursor[cid], 1);
    float a = y[3*i], b = y[3*i+1], c = y[3*i+2];
    ypc[pos]  = make_float4(a, b, c, (a*a + b*b) + c*c);   // (y**2).sum(1) order
    aidx[pos] = i;
}

// ================= top-k primitive =================
// Top-16 in lanes 0..15 sorted ascending by (d2, idx) lexicographic ==
// jax.lax.top_k tie semantics; deterministic regardless of traversal order.
__device__ __forceinline__ void topk_process(float d2, int ai, int lane,
        float& Ld, int& Li, float& kth, int& kidx, bool& filled) {
    const float INF = __builtin_inff();
    if (!filled) {                                  // bitonic-sort fill (wave-uniform)
        float v = d2; int ix = ai;
#pragma unroll
        for (int k = 2; k <= 64; k <<= 1)
#pragma unroll
            for (int j = k >> 1; j > 0; j >>= 1) {
                float ov = __shfl_xor(v, j);
                int   oi = __shfl_xor(ix, j);
                bool keepmin = (((lane & k) == 0) == ((lane & j) == 0));
                bool oless   = (ov < v) || (ov == v && oi < ix);
                bool take    = (keepmin == oless);
                v  = take ? ov : v;
                ix = take ? oi : ix;
            }
        Ld = (lane < KNN) ? v : INF;
        Li = (lane < KNN) ? ix : 0x7fffffff;
        kth  = readlane_f(v, 15);
        kidx = __builtin_amdgcn_readlane(ix, 15);
        filled = true;
        return;
    }
    bool adm = (d2 < kth) || (d2 == kth && ai < kidx);
    unsigned long long cand = __ballot(adm);
    if (cand) {
        do {
            int src = __builtin_ctzll(cand);
            cand &= cand - 1;
            float v  = readlane_f(d2, src);
            int   mi = __builtin_amdgcn_readlane(ai, src);
            bool pred = (Ld > v) || (Ld == v && Li > mi);   // lexicographic
            unsigned long long bal = __ballot(pred);
            int ins = __builtin_ctzll(bal);
            float pd = __shfl_up(Ld, 1);
            int   pi = __shfl_up(Li, 1);
            bool atins = (lane == ins);
            float tv = atins ? v  : pd;
            int   ti = atins ? mi : pi;
            Ld = pred ? tv : Ld;
            Li = pred ? ti : Li;
        } while (cand);
        kth  = readlane_f(Ld, 15);
        kidx = __builtin_amdgcn_readlane(Li, 15);
    }
}

// ================= fat kernel: knn query (blocks 0..4999) + A precompute =================
// Neither body uses __syncthreads -> block-divergent merge is safe. knn blocks
// dispatch first; precompute blocks fill the knn straggler tail.
__global__ __launch_bounds__(256) void knn_pre(
        const float* __restrict__ x, const float* __restrict__ y,
        const int* __restrict__ starts, const float4* __restrict__ ypc,
        const int* __restrict__ aidx,
        int* __restrict__ oidx, float* __restrict__ odist,
        const float* __restrict__ feats, const float* __restrict__ W1,
        const float* __restrict__ b1, _Float16* __restrict__ A) {
    __shared__ int s_start[4][64];
    __shared__ int s_off[4][64];
    const int lane = threadIdx.x & 63;
    const int wid  = threadIdx.x >> 6;

    if (blockIdx.x >= KNN_NBLK) {
        // ---------- per-atom precompute: A[l][i] = feats[i] @ W1[l][64:128] + b1[l] (fp16) ----------
        int id = (blockIdx.x - KNN_NBLK) * 4 + wid;
        if (id >= NLAYERS * A_GROUPS) return;
        int l = id / A_GROUPS, g = id - l * A_GROUPS;
        int base_atom = g * 8;

        float f[8];
#pragma unroll
        for (int a = 0; a < 8; ++a) f[a] = feats[(base_atom + a) * DAT + lane];
        float a0[8], a1[8], a2[8];
#pragma unroll
        for (int a = 0; a < 8; ++a) { a0[a] = 0.f; a1[a] = 0.f; a2[a] = 0.f; }

        const float* Wl = W1 + (size_t)l * HID * HID;
#pragma unroll 4
        for (int d = 0; d < DAT; ++d) {
            const float* row = Wl + (64 + d) * HID;
            float w0 = row[2 * lane];
            float w1 = row[2 * lane + 1];
            float w2 = row[128];
#pragma unroll
            for (int a = 0; a < 8; ++a) {
                float s = readlane_f(f[a], d);
                a0[a] += s * w0;
                a1[a] += s * w1;
                a2[a] += s * w2;
            }
        }
        const float* b1l = b1 + l * HID;
        float bb0 = b1l[2 * lane], bb1 = b1l[2 * lane + 1], bb2 = b1l[128];
#pragma unroll
        for (int a = 0; a < 8; ++a) {
            _Float16* Ar = A + ((size_t)l * M_ATOMS + base_atom + a) * A_HSTRIDE;
            half2_t hv; hv.x = (_Float16)(a0[a] + bb0); hv.y = (_Float16)(a1[a] + bb1);
            ((half2_t*)Ar)[lane] = hv;
            if (lane == 0) Ar[128] = (_Float16)(a2[a] + bb2);
        }
        return;
    }

    // ---------- kNN query (round-10 verified body) ----------
    const int n = blockIdx.x * 4 + wid;             // < 20000
    const float INF = __builtin_inff();

    const float qx = x[3*n], qy = x[3*n+1], qz = x[3*n+2];
    const float qs = (qx*qx + qy*qy) + qz*qz;       // (x**2).sum(1) order
    const int cx = cell_of(qx), cy = cell_of(qy), cz = cell_of(qz);

    float Ld = INF; int Li = 0x7fffffff;
    float kth = INF; int kidx = 0x7fffffff;
    bool filled = false;

    // rings 0..1: 9 contiguous x-runs, serial, center row first
    {
        int sS = 0, cnt = 0;
        if (lane < 9) {
            int dyv = lane % 3 - 1, dzv = lane / 3 - 1;
            int ny = cy + dyv, nz = cz + dzv;
            if (ny >= 0 && ny < GRIDL && nz >= 0 && nz < GRIDL) {
                int xl = max(cx - 1, 0), xh = min(cx + 1, GRIDL - 1);
                int cid0 = (nz * GRIDL + ny) * GRIDL + xl;
                sS  = starts[cid0];
                cnt = starts[cid0 + (xh - xl) + 1] - sS;
            }
        }
#pragma unroll
        for (int si = 0; si < 9; ++si) {
            const int s = (si == 0) ? 4 : (si <= 4 ? si - 1 : si);  // {4,0,1,2,3,5,6,7,8}
            const int ss = __builtin_amdgcn_readlane(sS, s);
            const int cc = __builtin_amdgcn_readlane(cnt, s);
            for (int b = 0; b < cc; b += 64) {
                int pos = b + lane; bool val = pos < cc;
                int a = val ? (ss + pos) : ss;
                float4 av = ypc[a];
                int    ai = aidx[a];
                float dot = (qx * av.x + qy * av.y) + qz * av.z;
                float d2  = (qs - 2.f * dot) + av.w;   // same algebra as reference
                if (!val) { d2 = INF; ai = 0x7fffffff; }
                topk_process(d2, ai, lane, Ld, Li, kth, kidx, filled);
            }
        }
    }

    // shells r>=2 (rare): lane-parallel segments + binary search
    int R = 1;
    while (R < GRIDL) {
        float bnd = (float)R * CELL_H - 0.125f;     // margin covers d2 rounding
        if (bnd * bnd > kth) break;                 // wave-uniform
        const int r  = R + 1;
        const int n1 = 2 * r + 1, m = 2 * r - 1;
        const int C1 = 2 * n1, C2 = 2 * m;
        const int S  = C1 + C2 + 2 * m * m;
        for (int base = 0; base < S; base += 64) {
            int sid = base + lane;
            int sS = 0, cnt = 0;
            if (sid < S) {
                int dy, dz, xlo, xhi;
                if (sid < C1) {
                    dz = (sid < n1) ? -r : r;
                    dy = (sid - ((sid < n1) ? 0 : n1)) - r;
                    xlo = cx - r; xhi = cx + r;
                } else if (sid < C1 + C2) {
                    int i = sid - C1;
                    dy = (i < m) ? -r : r;
                    dz = (i - ((i < m) ? 0 : m)) - (r - 1);
                    xlo = cx - r; xhi = cx + r;
                } else {
                    int i = sid - C1 - C2;
                    int pair = i >> 1, side = i & 1;
                    dz = (pair / m) - (r - 1);
                    dy = (pair % m) - (r - 1);
                    int xx = side ? cx + r : cx - r;
                    xlo = xx; xhi = xx;
                }
                int ny = cy + dy, nz = cz + dz;
                if (ny >= 0 && ny < GRIDL && nz >= 0 && nz < GRIDL) {
                    int xl = max(xlo, 0), xh = min(xhi, GRIDL - 1);
                    if (xl <= xh) {
                        int cid0 = (nz * GRIDL + ny) * GRIDL + xl;
                        sS  = starts[cid0];
                        cnt = starts[cid0 + (xh - xl) + 1] - sS;
                    }
                }
            }
            int incl = cnt;
#pragma unroll
            for (int o = 1; o < 64; o <<= 1) {
                int v = __shfl_up(incl, o);
                if (lane >= o) incl += v;
            }
            const int T = __builtin_amdgcn_readlane(incl, 63);
            if (T == 0) continue;
            s_start[wid][lane] = sS;
            s_off[wid][lane]   = incl - cnt;
            for (int b = 0; b < T; b += 64) {
                int pos = b + lane; bool val = pos < T;
                int c = 0;
                c += (s_off[wid][c + 32] <= pos) ? 32 : 0;
                c += (s_off[wid][c + 16] <= pos) ? 16 : 0;
                c += (s_off[wid][c + 8]  <= pos) ? 8  : 0;
                c += (s_off[wid][c + 4]  <= pos) ? 4  : 0;
                c += (s_off[wid][c + 2]  <= pos) ? 2  : 0;
                c += (s_off[wid][c + 1]  <= pos) ? 1  : 0;
                int a = s_start[wid][c] + (pos - s_off[wid][c]);
                a = val ? a : 0;
                float4 av = ypc[a];
                int    ai = aidx[a];
                float dot = (qx * av.x + qy * av.y) + qz * av.z;
                float d2  = (qs - 2.f * dot) + av.w;
                if (!val) { d2 = INF; ai = 0x7fffffff; }
                topk_process(d2, ai, lane, Ld, Li, kth, kidx, filled);
            }
        }
        R = r;
    }

    if (lane < KNN) {
        int ii = Li;
        float ax = y[3*ii], ay = y[3*ii+1], az = y[3*ii+2];
        float ddx = qx - ax, ddy = qy - ay, ddz = qz - az;
        float dist = (ddx*ddx + ddy*ddy) + ddz*ddz;   // ((x-y)**2).sum(-1) order
        oidx [n * KNN + lane] = ii;
        odist[n * KNN + lane] = dist;
    }
}

// ================= fused 3-layer MLP + groupnorm =================
// fp16 weights in LDS (32KB -> 4 blocks/CU); mixed-precision FMA (fp32 acc);
// one ds_read serves both points of the wave; A-gather offsets hoisted.
__global__ __launch_bounds__(512, 8) void mlp_fused(
        const float* __restrict__ W1, const float* __restrict__ W2,
        const float* __restrict__ b2, const float* __restrict__ gnw,
        const float* __restrict__ gnb, const _Float16* __restrict__ A,
        const int* __restrict__ oidx, const float* __restrict__ odist,
        float* __restrict__ out) {
    __shared__ half2_t w1h[64 * 64];  // 16KB [d][lane] = fp16(W1[d][2l], W1[d][2l+1])
    __shared__ half2_t w2h[64 * 64];  // 16KB [j][lane] = fp16(W2[2j][l], W2[2j+1][l])
    const int wave = threadIdx.x >> 6, lane = threadIdx.x & 63;
    const int n0 = (blockIdx.x * 8 + wave) * 2;     // 1250*8*2 == 20000

    int ikl0 = 0, ikl1 = 0; float dkl0 = 0.f, dkl1 = 0.f;
    if (lane < KNN) {
        ikl0 = oidx[n0 * KNN + lane];       dkl0 = odist[n0 * KNN + lane];
        ikl1 = oidx[(n0 + 1) * KNN + lane]; dkl1 = odist[(n0 + 1) * KNN + lane];
    }
    const int ho0 = ikl0 * A_HSTRIDE;               // half-offsets (valid lanes<16)
    const int ho1 = ikl1 * A_HSTRIDE;
    float pe0 = 1.f, pe1 = 1.f;

    for (int l = 0; l < NLAYERS; ++l) {
        if (l) __syncthreads();                     // prev layer done reading LDS
        const float* Wl  = W1 + (size_t)l * HID * HID;
        const float* W2l = W2 + (size_t)l * HID * DAT;
        for (int d = wave; d < 64; d += 8) {
            half2_t a; a.x = (_Float16)Wl[d * HID + 2 * lane];
                       a.y = (_Float16)Wl[d * HID + 2 * lane + 1];
            w1h[d * 64 + lane] = a;
            half2_t b; b.x = (_Float16)W2l[(2 * d) * DAT + lane];
                       b.y = (_Float16)W2l[(2 * d + 1) * DAT + lane];
            w2h[d * 64 + lane] = b;
        }
        const float wl0 = Wl[128 * HID + 2 * lane], wl1 = Wl[128 * HID + 2 * lane + 1];
        const float wl2 = Wl[128 * HID + 128];
        const float w1c = Wl[lane * HID + 128];
        const float w2c = W2l[128 * DAT + lane];
        const float b2v = 16.f * b2[l * DAT + lane];
        const float gw  = gnw[l * DAT + lane], gb = gnb[l * DAT + lane];

        // A-gathers issued before the staging barrier (latency hidden under it)
        const _Float16* Al = A + (size_t)l * M_ATOMS * A_HSTRIDE;
        half2_t Av0[KNN], Av1[KNN];
#pragma unroll
        for (int k = 0; k < KNN; ++k) {
            Av0[k] = ((const half2_t*)(Al + __builtin_amdgcn_readlane(ho0, k)))[lane];
            Av1[k] = ((const half2_t*)(Al + __builtin_amdgcn_readlane(ho1, k)))[lane];
        }
        float A2l0 = 0.f, A2l1 = 0.f;               // lane k: channel-128 of neighbor k
        if (lane < KNN) {
            A2l0 = (float)Al[ho0 + 128];
            A2l1 = (float)Al[ho1 + 128];
        }
        __syncthreads();                            // weights staged

        // p = pe @ W1[:64] ; channels (2l, 2l+1) per lane + ch 128 via reduce
        float p00, p01, p02, p10, p11, p12;
        if (l == 0) {                               // pe == 1: point-independent
            float fa = 0.f, fb = 0.f;
#pragma unroll 8
            for (int d = 0; d < 64; ++d) {
                half2_t w = w1h[d * 64 + lane];
                fa += (float)w.x; fb += (float)w.y;
            }
            float v = w1c;
            v += __shfl_xor(v, 1);  v += __shfl_xor(v, 2);  v += __shfl_xor(v, 4);
            v += __shfl_xor(v, 8);  v += __shfl_xor(v, 16); v += __shfl_xor(v, 32);
            p00 = p10 = fa; p01 = p11 = fb; p02 = p12 = v;
        } else {
            p00 = 0.f; p01 = 0.f; p10 = 0.f; p11 = 0.f;
#pragma unroll 8
            for (int d = 0; d < 64; ++d) {
                float s0 = readlane_f(pe0, d), s1 = readlane_f(pe1, d);
                half2_t w = w1h[d * 64 + lane];     // one read serves both points
                p00 += (float)w.x * s0; p01 += (float)w.y * s0;
                p10 += (float)w.x * s1; p11 += (float)w.y * s1;
            }
            float v0 = pe0 * w1c, v1 = pe1 * w1c;
            v0 += __shfl_xor(v0, 1);  v1 += __shfl_xor(v1, 1);
            v0 += __shfl_xor(v0, 2);  v1 += __shfl_xor(v1, 2);
            v0 += __shfl_xor(v0, 4);  v1 += __shfl_xor(v1, 4);
            v0 += __shfl_xor(v0, 8);  v1 += __shfl_xor(v1, 8);
            v0 += __shfl_xor(v0, 16); v1 += __shfl_xor(v1, 16);
            v0 += __shfl_xor(v0, 32); v1 += __shfl_xor(v1, 32);
            p02 = v0; p12 = v1;
        }

        // hsum = sum_k leaky(p + A[idx_k] + dist_k * wl), both points
        float hs00 = 0.f, hs01 = 0.f, hs02 = 0.f;
        float hs10 = 0.f, hs11 = 0.f, hs12 = 0.f;
#pragma unroll
        for (int k = 0; k < KNN; ++k) {
            float dd0 = readlane_f(dkl0, k), A20 = readlane_f(A2l0, k);
            float h0 = p00 + (float)Av0[k].x + dd0 * wl0; h0 = h0 >= 0.f ? h0 : 0.2f * h0; hs00 += h0;
            float h1 = p01 + (float)Av0[k].y + dd0 * wl1; h1 = h1 >= 0.f ? h1 : 0.2f * h1; hs01 += h1;
            float h2 = p02 + A20            + dd0 * wl2; h2 = h2 >= 0.f ? h2 : 0.2f * h2; hs02 += h2;
            float dd1 = readlane_f(dkl1, k), A21 = readlane_f(A2l1, k);
            float g0 = p10 + (float)Av1[k].x + dd1 * wl0; g0 = g0 >= 0.f ? g0 : 0.2f * g0; hs10 += g0;
            float g1 = p11 + (float)Av1[k].y + dd1 * wl1; g1 = g1 >= 0.f ? g1 : 0.2f * g1; hs11 += g1;
            float g2 = p12 + A21            + dd1 * wl2; g2 = g2 >= 0.f ? g2 : 0.2f * g2; hs12 += g2;
        }

        // msg = hsum @ W2 + K*b2, both points share each ds_read
        float m0 = 0.f, m1 = 0.f;
#pragma unroll 8
        for (int j = 0; j < 64; ++j) {
            float a0 = readlane_f(hs00, j), a1 = readlane_f(hs01, j);
            float c0 = readlane_f(hs10, j), c1 = readlane_f(hs11, j);
            half2_t w = w2h[j * 64 + lane];
            m0 += (float)w.x * a0; m0 += (float)w.y * a1;
            m1 += (float)w.x * c0; m1 += (float)w.y * c1;
        }
        m0 += hs02 * w2c + b2v;
        m1 += hs12 * w2c + b2v;

        // GroupNorm(2 groups of 32 channels) + leaky + residual, per point
        {
            float s1 = m0;
            s1 += __shfl_xor(s1, 1);  s1 += __shfl_xor(s1, 2);  s1 += __shfl_xor(s1, 4);
            s1 += __shfl_xor(s1, 8);  s1 += __shfl_xor(s1, 16);
            float mu = s1 * (1.f / 32.f);
            float dm = m0 - mu;
            float s2 = dm * dm;
            s2 += __shfl_xor(s2, 1);  s2 += __shfl_xor(s2, 2);  s2 += __shfl_xor(s2, 4);
            s2 += __shfl_xor(s2, 8);  s2 += __shfl_xor(s2, 16);
            float var = s2 * (1.f / 32.f);
            float g = dm * (1.f / sqrtf(var + 1e-5f)) * gw + gb;
            pe0 += (g >= 0.f) ? g : 0.2f * g;
        }
        {
            float s1 = m1;
            s1 += __shfl_xor(s1, 1);  s1 += __shfl_xor(s1, 2);  s1 += __shfl_xor(s1, 4);
            s1 += __shfl_xor(s1, 8);  s1 += __shfl_xor(s1, 16);
            float mu = s1 * (1.f / 32.f);
            float dm = m1 - mu;
            float s2 = dm * dm;
            s2 += __shfl_xor(s2, 1);  s2 += __shfl_xor(s2, 2);  s2 += __shfl_xor(s2, 4);
            s2 += __shfl_xor(s2, 8);  s2 += __shfl_xor(s2, 16);
            float var = s2 * (1.f / 32.f);
            float g = dm * (1.f / sqrtf(var + 1e-5f)) * gw + gb;
            pe1 += (g >= 0.f) ? g : 0.2f * g;
        }
    }

    out[n0 * DAT + lane]       = pe0;
    out[(n0 + 1) * DAT + lane] = pe1;
}

// ---------------- launch ----------------
extern "C" void kernel_launch(void* const* d_in, const int* in_sizes, int n_in,
                              void* d_out, int out_size, void* d_ws, size_t ws_size,
                              hipStream_t stream) {
    const float* x     = (const float*)d_in[0];
    const float* y     = (const float*)d_in[1];
    const float* feats = (const float*)d_in[2];
    const float* W1    = (const float*)d_in[3];
    const float* b1    = (const float*)d_in[4];
    const float* W2    = (const float*)d_in[5];
    const float* b2    = (const float*)d_in[6];
    const float* gnw   = (const float*)d_in[7];
    const float* gnb   = (const float*)d_in[8];
    float* out = (float*)d_out;

    char* ws = (char*)d_ws;
    float4*    ypc   = (float4*)  ws;                        // 160,000 B
    int*       oidx  = (int*)    (ws + 160000);              // 1,280,000 B
    float*     odist = (float*)  (ws + 1440000);             // 1,280,000 B
    _Float16*  A     = (_Float16*)(ws + 2720000);            // 7,920,000 B
    int*       starts= (int*)    (ws + 10640000);            // (13824+1)*4
    int*       cursor= (int*)    (ws + 10700000);            // 13824*4
    int*       counts= (int*)    (ws + 10760000);            // (13824+1)*4
    int*       acell = (int*)    (ws + 10820000);            // 10000*4
    int*       aidx  = (int*)    (ws + 10860000);            // 10000*4
    // total ~10.9 MB of ws

    grid_zero   <<<dim3((NCELL + 256) / 256), dim3(256), 0, stream>>>(counts);
    grid_count  <<<dim3((M_ATOMS + 255) / 256), dim3(256), 0, stream>>>(y, counts, acell);
    grid_scan   <<<dim3(1), dim3(1024), 0, stream>>>(counts, starts, cursor);
    grid_scatter<<<dim3((M_ATOMS + 255) / 256), dim3(256), 0, stream>>>(y, acell, cursor, ypc, aidx);
    knn_pre     <<<dim3(KNN_NBLK + PRE_NBLK), dim3(256), 0, stream>>>(
                    x, y, starts, ypc, aidx, oidx, odist, feats, W1, b1, A);
    mlp_fused   <<<dim3(1250), dim3(512), 0, stream>>>(W1, W2, b2, gnw, gnb, A, oidx, odist, out);
}